// Round 3
// baseline (6472.709 us; speedup 1.0000x reference)
//
#include <hip/hip_runtime.h>
#include <hip/hip_bf16.h>

#define NUM_H 8
#define DIM 16
#define HD 128
#define IN_F 256
#define E_F 64
#define NEG_SLOPE 0.2f

__device__ __forceinline__ float tof(float x) { return x; }
__device__ __forceinline__ float tof(__hip_bfloat16 x) { return __bfloat162float(x); }
__device__ __forceinline__ void stout(float* p, size_t i, float v) { p[i] = v; }
__device__ __forceinline__ void stout(__hip_bfloat16* p, size_t i, float v) { p[i] = __float2bfloat16(v); }
__device__ __forceinline__ float b2f(__hip_bfloat16 x) { return __bfloat162float(x); }

// ---------------- detector: is input data f32 or bf16? ----------------
// Scan Wl (32768 elements, true values |x|<0.5) interpreted as bf16 halves.
// If underlying data is f32, low-mantissa halves have uniform random exponents
// -> |x|>=512 or NaN appears w.p. ~0.47 per junk half. flag=1 means f32.
__global__ void k_detect(const unsigned short* __restrict__ w, int n_half, int* flag) {
    __shared__ int s;
    if (threadIdx.x == 0) s = 0;
    __syncthreads();
    int bad = 0;
    for (int i = threadIdx.x; i < n_half; i += blockDim.x) {
        int e = (w[i] >> 7) & 0xFF;
        if (e >= 136) bad = 1;  // |x| >= 512, or Inf/NaN
    }
    if (bad) atomicOr(&s, 1);
    __syncthreads();
    if (threadIdx.x == 0) *flag = s;
}

// ---------------- K0: zero workspace regions (agg + nsum) ----------------
__global__ void k_zero(float* p, long long n) {
    long long i = (long long)blockIdx.x * blockDim.x + threadIdx.x;
    long long stride = (long long)gridDim.x * blockDim.x;
    for (; i < n; i += stride) p[i] = 0.0f;
}

// ---------------- K1: node projections left/right/value ----------------
template <typename T>
__device__ __forceinline__ void proj_impl(
        const void* nf_, const void* Wl_, const void* bl_,
        const void* Wr_, const void* br_, const void* Wv_, const void* bv_,
        __hip_bfloat16* __restrict__ left, __hip_bfloat16* __restrict__ right,
        __hip_bfloat16* __restrict__ val, int n_nodes) {
    const T* nf = (const T*)nf_;
    const T* Wl = (const T*)Wl_; const T* bl = (const T*)bl_;
    const T* Wr = (const T*)Wr_; const T* br = (const T*)br_;
    const T* Wv = (const T*)Wv_; const T* bv = (const T*)bv_;
    __shared__ float srow[IN_F];
    int node = blockIdx.x;
    if (node >= n_nodes) return;
    int j = threadIdx.x;  // 0..127
    srow[j]       = tof(nf[(size_t)node * IN_F + j]);
    srow[j + 128] = tof(nf[(size_t)node * IN_F + j + 128]);
    __syncthreads();
    float aL = tof(bl[j]);
    float aR = tof(br[j]);
    float aV = tof(bv[j]);
#pragma unroll 4
    for (int k = 0; k < IN_F; k++) {
        float f = srow[k];
        aL += f * tof(Wl[k * HD + j]);
        aR += f * tof(Wr[k * HD + j]);
        aV += f * tof(Wv[k * HD + j]);
    }
    size_t o = (size_t)node * HD + j;
    left[o]  = __float2bfloat16(aL);
    right[o] = __float2bfloat16(aR);
    val[o]   = __float2bfloat16(aV);
}

__global__ void k_proj(const void* nf, const void* Wl, const void* bl,
                       const void* Wr, const void* br, const void* Wv, const void* bv,
                       __hip_bfloat16* left, __hip_bfloat16* right, __hip_bfloat16* val,
                       const int* __restrict__ flag, int n_nodes) {
    if (*flag) proj_impl<float>(nf, Wl, bl, Wr, br, Wv, bv, left, right, val, n_nodes);
    else       proj_impl<__hip_bfloat16>(nf, Wl, bl, Wr, br, Wv, bv, left, right, val, n_nodes);
}

// ---------------- K2: fused edge scoring + exp + scatter-aggregate ----------
template <typename T>
__device__ __forceinline__ void edge_impl(
        const int* __restrict__ eidx, const void* ef_, const void* We_,
        const void* be_, const void* av_,
        const __hip_bfloat16* __restrict__ left, const __hip_bfloat16* __restrict__ right,
        const __hip_bfloat16* __restrict__ val,
        float* __restrict__ nsum, float* __restrict__ agg, int n_edges) {
    const T* ef = (const T*)ef_; const T* We = (const T*)We_;
    const T* be = (const T*)be_; const T* av = (const T*)av_;
    int gid = blockIdx.x * blockDim.x + threadIdx.x;
    int e = gid >> 3;
    int h = gid & 7;
    if (e >= n_edges) return;
    int s = eidx[e];            // sources = edge_index[0]
    int t = eidx[n_edges + e];  // targets = edge_index[1]

    // edge bias: (ef row) @ We[:, h] + be[h]
    float sc = tof(be[h]);
    const T* efr = ef + (size_t)e * E_F;
#pragma unroll 8
    for (int k = 0; k < E_F; k++) sc += tof(efr[k]) * tof(We[k * NUM_H + h]);

    // GATv2 attention dot
    const __hip_bfloat16* L = left  + (size_t)t * HD + h * DIM;
    const __hip_bfloat16* R = right + (size_t)s * HD + h * DIM;
#pragma unroll
    for (int d = 0; d < DIM; d++) {
        float x = b2f(L[d]) + b2f(R[d]);
        x = x > 0.0f ? x : NEG_SLOPE * x;
        sc += x * tof(av[h * DIM + d]);
    }

    float es = expf(sc);
    atomicAdd(nsum + (size_t)t * NUM_H + h, es);

    const __hip_bfloat16* V = val + (size_t)s * HD + h * DIM;
    float* A = agg + (size_t)t * HD + h * DIM;
#pragma unroll
    for (int d = 0; d < DIM; d++) atomicAdd(A + d, es * b2f(V[d]));
}

__global__ void k_edge(const int* eidx, const void* ef, const void* We, const void* be,
                       const void* av, const __hip_bfloat16* left, const __hip_bfloat16* right,
                       const __hip_bfloat16* val, float* nsum, float* agg,
                       const int* __restrict__ flag, int n_edges) {
    if (*flag) edge_impl<float>(eidx, ef, We, be, av, left, right, val, nsum, agg, n_edges);
    else       edge_impl<__hip_bfloat16>(eidx, ef, We, be, av, left, right, val, nsum, agg, n_edges);
}

// ---------------- K4: normalize + output projection ----------------
template <typename T>
__device__ __forceinline__ void out_impl(
        const float* __restrict__ agg, const float* __restrict__ nsum,
        const void* Wo_, const void* bo_, void* out_, int n_nodes) {
    const T* Wo = (const T*)Wo_; const T* bo = (const T*)bo_;
    T* out = (T*)out_;
    __shared__ float srow[HD];
    int node = blockIdx.x;
    if (node >= n_nodes) return;
    int j = threadIdx.x;  // 0..127
    int h = j >> 4;
    srow[j] = agg[(size_t)node * HD + j] / (nsum[(size_t)node * NUM_H + h] + 1e-10f);
    __syncthreads();
    float a = tof(bo[j]);
#pragma unroll 4
    for (int k = 0; k < HD; k++) a += srow[k] * tof(Wo[k * HD + j]);
    stout(out, (size_t)node * HD + j, a);
}

__global__ void k_out(const float* agg, const float* nsum,
                      const void* Wo, const void* bo, void* out,
                      const int* __restrict__ flag, int n_nodes) {
    if (*flag) out_impl<float>(agg, nsum, Wo, bo, out, n_nodes);
    else       out_impl<__hip_bfloat16>(agg, nsum, Wo, bo, out, n_nodes);
}

extern "C" void kernel_launch(void* const* d_in, const int* in_sizes, int n_in,
                              void* d_out, int out_size, void* d_ws, size_t ws_size,
                              hipStream_t stream) {
    const void* nf = d_in[0];
    const int* eidx = (const int*)d_in[1];
    const void* ef = d_in[2];
    const void* Wl = d_in[3];
    const void* bl = d_in[4];
    const void* Wr = d_in[5];
    const void* br = d_in[6];
    const void* We = d_in[7];
    const void* be = d_in[8];
    const void* av = d_in[9];
    const void* Wv = d_in[10];
    const void* bv = d_in[11];
    const void* Wo = d_in[12];
    const void* bo = d_in[13];

    const int n_nodes = in_sizes[0] / IN_F;   // 50000
    const int n_edges = in_sizes[1] / 2;      // 800000

    // workspace layout (~52.9 MB):
    //   flag  int   (256 B slot)
    //   agg   f32  [n_nodes*HD]     25.6 MB  (atomic target, zeroed)
    //   nsum  f32  [n_nodes*NUM_H]   1.6 MB  (atomic target, zeroed)
    //   left  bf16 [n_nodes*HD]     12.8 MB
    //   right bf16 [n_nodes*HD]     12.8 MB
    // val bf16 [n_nodes*HD] lives in d_out (dead space until k_out rewrites it)
    int* flag = (int*)d_ws;
    float* agg  = (float*)((char*)d_ws + 256);
    float* nsum = agg + (size_t)n_nodes * HD;
    __hip_bfloat16* left  = (__hip_bfloat16*)(nsum + (size_t)n_nodes * NUM_H);
    __hip_bfloat16* right = left + (size_t)n_nodes * HD;
    __hip_bfloat16* val   = (__hip_bfloat16*)d_out;

    // detect input dtype (f32 vs bf16) from Wl's bit patterns
    k_detect<<<1, 256, 0, stream>>>((const unsigned short*)Wl, 32768, flag);

    // K0: zero agg + nsum (contiguous region)
    long long n_zero = (long long)n_nodes * HD + (long long)n_nodes * NUM_H;
    k_zero<<<2048, 256, 0, stream>>>(agg, n_zero);

    // K1: projections
    k_proj<<<n_nodes, 128, 0, stream>>>(nf, Wl, bl, Wr, br, Wv, bv, left, right, val, flag, n_nodes);

    // K2: fused edge scoring + scatter
    {
        long long total = (long long)n_edges * NUM_H;
        int blocks = (int)((total + 255) / 256);
        k_edge<<<blocks, 256, 0, stream>>>(eidx, ef, We, be, av, left, right, val, nsum, agg, flag, n_edges);
    }

    // K4: normalize + output projection (fully rewrites d_out)
    k_out<<<n_nodes, 128, 0, stream>>>(agg, nsum, Wo, bo, d_out, flag, n_nodes);
}

// Round 4
// 1054.387 us; speedup vs baseline: 6.1388x; 6.1388x over previous
//
#include <hip/hip_runtime.h>
#include <hip/hip_bf16.h>

#define NUM_H 8
#define DIM 16
#define HD 128
#define IN_F 256
#define E_F 64
#define NEG_SLOPE 0.2f
#define NB 8  // nodes per block in k_proj / k_out (amortizes weight traffic)

__device__ __forceinline__ float b2f(__hip_bfloat16 x) { return __bfloat162float(x); }
__device__ __forceinline__ __hip_bfloat16 f2b(float x) { return __float2bfloat16(x); }

// ---------------- zero int array (deg) ----------------
__global__ void k_zero_int(int* p, int n) {
    int i = blockIdx.x * blockDim.x + threadIdx.x;
    int stride = gridDim.x * blockDim.x;
    for (; i < n; i += stride) p[i] = 0;
}

// ---------------- CSR build: histogram of targets ----------------
__global__ void k_hist(const int* __restrict__ eidx, int* __restrict__ deg, int n_edges) {
    int e = blockIdx.x * blockDim.x + threadIdx.x;
    if (e < n_edges) atomicAdd(&deg[eidx[n_edges + e]], 1);
}

// ---------------- CSR build: exclusive scan (single block) ----------------
__global__ void k_scan(const int* __restrict__ deg, int* __restrict__ offs,
                       int* __restrict__ cursor, int n) {
    __shared__ int part[1024];
    int tid = threadIdx.x;
    int chunk = (n + 1023) / 1024;
    int base = tid * chunk;
    int hi = base + chunk < n ? base + chunk : n;
    int sum = 0;
    for (int i = base; i < hi; i++) sum += deg[i];
    part[tid] = sum;
    __syncthreads();
    for (int off = 1; off < 1024; off <<= 1) {
        int v = (tid >= off) ? part[tid - off] : 0;
        __syncthreads();
        part[tid] += v;
        __syncthreads();
    }
    int run = (tid == 0) ? 0 : part[tid - 1];  // exclusive prefix of this chunk
    for (int i = base; i < hi; i++) {
        offs[i] = run;
        cursor[i] = run;
        run += deg[i];
    }
    if (tid == 0) offs[n] = part[1023];
}

// ---------------- CSR build: scatter edge ids into slots ----------------
__global__ void k_scatter(const int* __restrict__ eidx, int* __restrict__ cursor,
                          int* __restrict__ eid, int n_edges) {
    int e = blockIdx.x * blockDim.x + threadIdx.x;
    if (e >= n_edges) return;
    int t = eidx[n_edges + e];
    int pos = atomicAdd(&cursor[t], 1);
    eid[pos] = e;
}

// ---------------- K1: node projections, NB nodes per block ----------------
__global__ void k_proj(const float* __restrict__ nf,
                       const float* __restrict__ Wl, const float* __restrict__ bl,
                       const float* __restrict__ Wr, const float* __restrict__ br,
                       const float* __restrict__ Wv, const float* __restrict__ bv,
                       __hip_bfloat16* __restrict__ left, __hip_bfloat16* __restrict__ right,
                       __hip_bfloat16* __restrict__ val, int n_nodes) {
    __shared__ float srow[NB][IN_F];
    int node0 = blockIdx.x * NB;
    int j = threadIdx.x;  // 0..127 = output column
    for (int i = j; i < NB * IN_F; i += 128)
        srow[i / IN_F][i % IN_F] = nf[(size_t)node0 * IN_F + i];
    __syncthreads();
    float aL[NB], aR[NB], aV[NB];
    float bL = bl[j], bR = br[j], bV = bv[j];
#pragma unroll
    for (int n = 0; n < NB; n++) { aL[n] = bL; aR[n] = bR; aV[n] = bV; }
    for (int k = 0; k < IN_F; k++) {
        float wl = Wl[k * HD + j];
        float wr = Wr[k * HD + j];
        float wv = Wv[k * HD + j];
#pragma unroll
        for (int n = 0; n < NB; n++) {
            float f = srow[n][k];
            aL[n] += f * wl; aR[n] += f * wr; aV[n] += f * wv;
        }
    }
#pragma unroll
    for (int n = 0; n < NB; n++) {
        size_t o = (size_t)(node0 + n) * HD + j;
        left[o] = f2b(aL[n]); right[o] = f2b(aR[n]); val[o] = f2b(aV[n]);
    }
}

// ---------------- K2: edge scores, es = exp(score), no atomics ----------
__global__ void k_escore(const int* __restrict__ eidx, const float* __restrict__ ef,
                         const float* __restrict__ We, const float* __restrict__ be,
                         const float* __restrict__ av,
                         const __hip_bfloat16* __restrict__ left,
                         const __hip_bfloat16* __restrict__ right,
                         __hip_bfloat16* __restrict__ es, int n_edges) {
    int gid = blockIdx.x * blockDim.x + threadIdx.x;
    int e = gid >> 3;
    int h = gid & 7;
    if (e >= n_edges) return;
    int s = eidx[e];
    int t = eidx[n_edges + e];
    float sc = be[h];
    const float* efr = ef + (size_t)e * E_F;
#pragma unroll 8
    for (int k = 0; k < E_F; k++) sc += efr[k] * We[k * NUM_H + h];
    const __hip_bfloat16* L = left + (size_t)t * HD + h * DIM;
    const __hip_bfloat16* R = right + (size_t)s * HD + h * DIM;
#pragma unroll
    for (int d = 0; d < DIM; d++) {
        float x = b2f(L[d]) + b2f(R[d]);
        x = x > 0.0f ? x : NEG_SLOPE * x;
        sc += x * av[h * DIM + d];
    }
    es[(size_t)e * NUM_H + h] = f2b(expf(sc));
}

// ---------------- K3: gather-aggregate per node + normalize ----------------
__global__ void k_agg(const int* __restrict__ offs, const int* __restrict__ eid,
                      const int* __restrict__ eidx,
                      const __hip_bfloat16* __restrict__ es,
                      const __hip_bfloat16* __restrict__ val,
                      float* __restrict__ nagg, int n_nodes) {
    int t = blockIdx.x;
    if (t >= n_nodes) return;
    int j = threadIdx.x;  // 0..127
    int h = j >> 4;
    int beg = offs[t], end = offs[t + 1];
    float acc = 0.0f, wsum = 0.0f;
    for (int i = beg; i < end; i++) {
        int e = eid[i];
        int s = eidx[e];  // source of this edge
        float w = b2f(es[(size_t)e * NUM_H + h]);
        acc += w * b2f(val[(size_t)s * HD + j]);
        wsum += w;
    }
    nagg[(size_t)t * HD + j] = acc / (wsum + 1e-10f);
}

// ---------------- K4: output projection, NB nodes per block ----------------
__global__ void k_out(const float* __restrict__ nagg, const float* __restrict__ Wo,
                      const float* __restrict__ bo, float* __restrict__ out, int n_nodes) {
    __shared__ float srow[NB][HD];
    int node0 = blockIdx.x * NB;
    int j = threadIdx.x;  // 0..127
    for (int i = j; i < NB * HD; i += 128)
        srow[i / HD][i % HD] = nagg[(size_t)node0 * HD + i];
    __syncthreads();
    float a[NB];
    float b = bo[j];
#pragma unroll
    for (int n = 0; n < NB; n++) a[n] = b;
    for (int k = 0; k < HD; k++) {
        float w = Wo[k * HD + j];
#pragma unroll
        for (int n = 0; n < NB; n++) a[n] += srow[n][k] * w;
    }
#pragma unroll
    for (int n = 0; n < NB; n++) out[(size_t)(node0 + n) * HD + j] = a[n];
}

extern "C" void kernel_launch(void* const* d_in, const int* in_sizes, int n_in,
                              void* d_out, int out_size, void* d_ws, size_t ws_size,
                              hipStream_t stream) {
    const float* nf = (const float*)d_in[0];
    const int* eidx = (const int*)d_in[1];
    const float* ef = (const float*)d_in[2];
    const float* Wl = (const float*)d_in[3];
    const float* bl = (const float*)d_in[4];
    const float* Wr = (const float*)d_in[5];
    const float* br = (const float*)d_in[6];
    const float* We = (const float*)d_in[7];
    const float* be = (const float*)d_in[8];
    const float* av = (const float*)d_in[9];
    const float* Wv = (const float*)d_in[10];
    const float* bv = (const float*)d_in[11];
    const float* Wo = (const float*)d_in[12];
    const float* bo = (const float*)d_in[13];
    float* out = (float*)d_out;

    const int n_nodes = in_sizes[0] / IN_F;   // 50000
    const int n_edges = in_sizes[1] / 2;      // 800000
    const size_t NHD = (size_t)n_nodes * HD;  // 6.4M

    // workspace layout (~42.3 MB):
    //   [256B pad]
    //   left   bf16 [NHD]      12.8 MB   } nagg f32 [NHD] (25.6 MB) overlays
    //   right  bf16 [NHD]      12.8 MB   } left+right after escore is done
    //   es     bf16 [E*8]      12.8 MB
    //   deg    int  [N]        200 KB
    //   offs   int  [N+1]      200 KB
    //   cursor int  [N]        200 KB
    //   eid    int  [E]        3.2 MB
    // val bf16 [NHD] lives in d_out's first half (d_out = 25.6 MB f32);
    // k_agg reads val -> writes nagg (ws); k_out reads nagg -> rewrites d_out.
    char* base = (char*)d_ws;
    __hip_bfloat16* left  = (__hip_bfloat16*)(base + 256);
    __hip_bfloat16* right = left + NHD;
    __hip_bfloat16* es    = right + NHD;
    int* deg    = (int*)(es + (size_t)n_edges * NUM_H);
    int* offs   = deg + n_nodes;
    int* cursor = offs + n_nodes + 1;
    int* eid    = cursor + n_nodes;
    float* nagg = (float*)left;
    __hip_bfloat16* val = (__hip_bfloat16*)d_out;

    int eb = (n_edges + 255) / 256;  // 3125

    // CSR build
    k_zero_int<<<64, 256, 0, stream>>>(deg, n_nodes);
    k_hist<<<eb, 256, 0, stream>>>(eidx, deg, n_edges);
    k_scan<<<1, 1024, 0, stream>>>(deg, offs, cursor, n_nodes);
    k_scatter<<<eb, 256, 0, stream>>>(eidx, cursor, eid, n_edges);

    // projections (writes left/right in ws, val in d_out)
    k_proj<<<n_nodes / NB, 128, 0, stream>>>(nf, Wl, bl, Wr, br, Wv, bv,
                                             left, right, val, n_nodes);

    // edge scores
    k_escore<<<(n_edges * NUM_H + 255) / 256, 256, 0, stream>>>(
        eidx, ef, We, be, av, left, right, es, n_edges);

    // gather-aggregate + normalize (left/right dead -> nagg overlays them)
    k_agg<<<n_nodes, 128, 0, stream>>>(offs, eid, eidx, es, val, nagg, n_nodes);

    // output projection (fully rewrites d_out)
    k_out<<<n_nodes / NB, 128, 0, stream>>>(nagg, Wo, bo, out, n_nodes);
}